// Round 1
// baseline (29.985 us; speedup 1.0000x reference)
//
#include <hip/hip_runtime.h>

#define B_ 8
#define N_ 2048
#define F_ 128   // feature dim == out dim

// workspace layout (floats)
#define WS_PAJ   0            // [8][32] partial sums of a_j   (256)
#define WS_DIS   256          // [B*N] dis                     (16384)
#define WS_AIB   16640        // [B*N] a_i + adj_b             (16384)
#define WS_PS0   33024        // [8][32][128] partial S0       (32768)
#define WS_PS1   65792        // [8][32][128] partial S1       (32768)
// total 98560 floats = 394240 bytes

// -------- K1: per-batch column sums -> partial a_j sums --------
// grid 256 (8 batches x 32 row-blocks of 64 rows), block 256
__global__ void k1_colsum(const float* __restrict__ x,
                          const float* __restrict__ adj_w,
                          float* __restrict__ pAj) {
    __shared__ float cs[2][128];
    __shared__ float rv[128];
    const int bid = blockIdx.x;
    const int b = bid >> 5, mblk = bid & 31;
    const int r0 = mblk * 64;
    const int t = threadIdx.x;
    const int c = t & 127, g = t >> 7;
    const float* xp = x + (size_t)(b * N_ + r0) * F_;
    float acc = 0.f;
    for (int j = g; j < 64; j += 2)
        acc += xp[j * F_ + c];
    cs[g][c] = acc;
    __syncthreads();
    if (t < 128) {
        float tot = cs[0][t] + cs[1][t];
        rv[t] = tot * adj_w[F_ + t];   // dot column-sum with w2
    }
    __syncthreads();
    if (t < 64) {
        float s = rv[t] + rv[t + 64];
        #pragma unroll
        for (int off = 32; off > 0; off >>= 1)
            s += __shfl_down(s, off, 64);
        if (t == 0) pAj[b * 32 + mblk] = s;
    }
}

// -------- K2: out = x@W, dis, per-block partial S0/S1 --------
// grid 256 (8 batches x 32 blocks of 64 rows), block 256
__global__ __launch_bounds__(256) void k2_gemm(
    const float* __restrict__ x, const float* __restrict__ adj_w,
    const float* __restrict__ adj_b_p, const float* __restrict__ weight,
    const float* __restrict__ pAj,
    float* __restrict__ outx,          // == d_out
    float* __restrict__ dis_g, float* __restrict__ aib_g,
    float* __restrict__ pS0, float* __restrict__ pS1)
{
    // xT: transposed x tile, stride 68 (float4-aligned), rows XOR-swizzled:
    //   element (k,row) at xT[k*68 + ((rh ^ ((k>>2)&3))<<3) + rl], row = 8*rh+rl
    __shared__ float xT[128 * 68];
    __shared__ float wlds[32 * 132];   // W k-chunk; aliased as red[8][128] in epilogue
    __shared__ float adjw[256];
    __shared__ float pai[4][64], paj_[4][64];
    __shared__ float disb[64], ajd[64];
    __shared__ float pajsum[32];

    const int bid = blockIdx.x;
    const int b = bid >> 5, mblk = bid & 31;
    const int r0 = mblk * 64;
    const int t = threadIdx.x;
    const int tc = t & 31, tr = t >> 5;

    const float* xblk = x + (size_t)(b * N_ + r0) * F_;

    adjw[t] = adj_w[t];
    if (t < 32) pajsum[t] = pAj[b * 32 + t];

    // stage x tile transposed (coalesced float4 global reads)
    {
        const int k4 = tc * 4;
        #pragma unroll
        for (int p = 0; p < 8; ++p) {
            const int row = p * 8 + tr;
            const int rh = row >> 3, rl = row & 7;
            const float4 v = *reinterpret_cast<const float4*>(&xblk[row * F_ + k4]);
            const float vv[4] = {v.x, v.y, v.z, v.w};
            #pragma unroll
            for (int i = 0; i < 4; ++i) {
                const int k = k4 + i;
                xT[k * 68 + ((rh ^ ((k >> 2) & 3)) << 3) + rl] = vv[i];
            }
        }
    }
    // stage W chunk 0
    {
        const int c4 = tc * 4;
        #pragma unroll
        for (int p = 0; p < 4; ++p) {
            const int kk = p * 8 + tr;
            *reinterpret_cast<float4*>(&wlds[kk * 132 + c4]) =
                *reinterpret_cast<const float4*>(&weight[kk * F_ + c4]);
        }
    }
    __syncthreads();

    // a_i, a_j for the 64 rows (k split 4 ways across the block)
    {
        const int row = t & 63, half = t >> 6;
        const int rh = row >> 3, rl = row & 7;
        float ai = 0.f, aj = 0.f;
        for (int k = half * 32; k < half * 32 + 32; ++k) {
            const float v = xT[k * 68 + ((rh ^ ((k >> 2) & 3)) << 3) + rl];
            ai = fmaf(v, adjw[k], ai);
            aj = fmaf(v, adjw[128 + k], aj);
        }
        pai[half][row] = ai;
        paj_[half][row] = aj;
    }
    __syncthreads();
    if (t < 64) {
        const float ai = pai[0][t] + pai[1][t] + pai[2][t] + pai[3][t];
        const float aj = paj_[0][t] + paj_[1][t] + paj_[2][t] + paj_[3][t];
        float ajs = 0.f;
        for (int i = 0; i < 32; ++i) ajs += pajsum[i];
        const float adjb = adj_b_p[0];
        float deg = 2048.f * ai + ajs + 2048.f * adjb + 1.f;
        deg = fmaxf(deg, 1.f);
        const float d = rsqrtf(deg);
        disb[t] = d;
        ajd[t] = aj * d;
        dis_g[b * N_ + r0 + t] = d;
        aib_g[b * N_ + r0 + t] = ai + adjb;
    }
    __syncthreads();

    // main GEMM: thread owns rows tr*8..tr*8+7, cols {2tc,2tc+1,2tc+64,2tc+65}
    float acc[8][4];
    #pragma unroll
    for (int r = 0; r < 8; ++r)
        #pragma unroll
        for (int j = 0; j < 4; ++j) acc[r][j] = 0.f;

    for (int kc = 0; kc < 4; ++kc) {
        #pragma unroll 4
        for (int kk = 0; kk < 32; ++kk) {
            const int k = kc * 32 + kk;
            const int base = k * 68 + ((tr ^ ((k >> 2) & 3)) << 3);
            const float4 x0 = *reinterpret_cast<const float4*>(&xT[base]);
            const float4 x1 = *reinterpret_cast<const float4*>(&xT[base + 4]);
            const float2 w0 = *reinterpret_cast<const float2*>(&wlds[kk * 132 + 2 * tc]);
            const float2 w1 = *reinterpret_cast<const float2*>(&wlds[kk * 132 + 2 * tc + 64]);
            const float xr[8] = {x0.x, x0.y, x0.z, x0.w, x1.x, x1.y, x1.z, x1.w};
            const float wv[4] = {w0.x, w0.y, w1.x, w1.y};
            #pragma unroll
            for (int r = 0; r < 8; ++r)
                #pragma unroll
                for (int j = 0; j < 4; ++j)
                    acc[r][j] = fmaf(xr[r], wv[j], acc[r][j]);
        }
        __syncthreads();
        if (kc < 3) {
            const int c4 = tc * 4;
            #pragma unroll
            for (int p = 0; p < 4; ++p) {
                const int kk = p * 8 + tr;
                *reinterpret_cast<float4*>(&wlds[kk * 132 + c4]) =
                    *reinterpret_cast<const float4*>(&weight[((kc + 1) * 32 + kk) * F_ + c4]);
            }
            __syncthreads();
        }
    }

    // write out rows (coalesced float2)
    #pragma unroll
    for (int r = 0; r < 8; ++r) {
        const int row = tr * 8 + r;
        float* op = outx + (size_t)(b * N_ + r0 + row) * F_;
        *reinterpret_cast<float2*>(&op[2 * tc]) = make_float2(acc[r][0], acc[r][1]);
        *reinterpret_cast<float2*>(&op[2 * tc + 64]) = make_float2(acc[r][2], acc[r][3]);
    }

    // per-block partial S0/S1 over the 64 rows
    float ps0[4] = {0.f, 0.f, 0.f, 0.f}, ps1[4] = {0.f, 0.f, 0.f, 0.f};
    #pragma unroll
    for (int r = 0; r < 8; ++r) {
        const int row = tr * 8 + r;
        const float dv = disb[row], av = ajd[row];
        #pragma unroll
        for (int j = 0; j < 4; ++j) {
            ps0[j] = fmaf(dv, acc[r][j], ps0[j]);
            ps1[j] = fmaf(av, acc[r][j], ps1[j]);
        }
    }
    float* red = wlds;  // alias, safe: barrier after last wlds read above
    red[tr * 128 + 2 * tc]      = ps0[0];
    red[tr * 128 + 2 * tc + 1]  = ps0[1];
    red[tr * 128 + 2 * tc + 64] = ps0[2];
    red[tr * 128 + 2 * tc + 65] = ps0[3];
    __syncthreads();
    if (t < 128) {
        float s = 0.f;
        #pragma unroll
        for (int g2 = 0; g2 < 8; ++g2) s += red[g2 * 128 + t];
        pS0[(b * 32 + mblk) * 128 + t] = s;
    }
    __syncthreads();
    red[tr * 128 + 2 * tc]      = ps1[0];
    red[tr * 128 + 2 * tc + 1]  = ps1[1];
    red[tr * 128 + 2 * tc + 64] = ps1[2];
    red[tr * 128 + 2 * tc + 65] = ps1[3];
    __syncthreads();
    if (t < 128) {
        float s = 0.f;
        #pragma unroll
        for (int g2 = 0; g2 < 8; ++g2) s += red[g2 * 128 + t];
        pS1[(b * 32 + mblk) * 128 + t] = s;
    }
}

// -------- K3: reduce S0/S1, epilogue in place on d_out --------
// grid 256 (8 batches x 32 blocks of 64 rows), block 256
__global__ void k3_final(const float* __restrict__ dis_g,
                         const float* __restrict__ aib_g,
                         const float* __restrict__ pS0,
                         const float* __restrict__ pS1,
                         const float* __restrict__ bias,
                         float* __restrict__ outp) {
    __shared__ float s0[128], s1[128], disl[64], aibl[64], bl[128];
    const int bid = blockIdx.x;
    const int b = bid >> 5, mblk = bid & 31;
    const int r0 = mblk * 64;
    const int t = threadIdx.x;
    if (t < 128) {
        float s = 0.f;
        for (int kb = 0; kb < 32; ++kb) s += pS0[(b * 32 + kb) * 128 + t];
        s0[t] = s;
        bl[t] = bias[t];
    } else {
        const int c = t - 128;
        float s = 0.f;
        for (int kb = 0; kb < 32; ++kb) s += pS1[(b * 32 + kb) * 128 + c];
        s1[c] = s;
    }
    if (t < 64) {
        disl[t] = dis_g[b * N_ + r0 + t];
        aibl[t] = aib_g[b * N_ + r0 + t];
    }
    __syncthreads();
    const int c = t & 127, g = t >> 7;
    for (int rr = g; rr < 64; rr += 2) {
        const size_t idx = (size_t)(b * N_ + r0 + rr) * F_ + c;
        const float o = outp[idx];
        const float d = disl[rr];
        const float v = d * (aibl[rr] * s0[c] + s1[c] + d * o) + bl[c];
        outp[idx] = fmaxf(v, 0.f);
    }
}

extern "C" void kernel_launch(void* const* d_in, const int* in_sizes, int n_in,
                              void* d_out, int out_size, void* d_ws, size_t ws_size,
                              hipStream_t stream) {
    const float* x      = (const float*)d_in[0];
    const float* adj_w  = (const float*)d_in[1];
    const float* adj_b  = (const float*)d_in[2];
    const float* weight = (const float*)d_in[3];
    const float* bias   = (const float*)d_in[4];
    float* out = (float*)d_out;
    float* ws  = (float*)d_ws;

    float* pAj = ws + WS_PAJ;
    float* dis = ws + WS_DIS;
    float* aib = ws + WS_AIB;
    float* pS0 = ws + WS_PS0;
    float* pS1 = ws + WS_PS1;

    k1_colsum<<<256, 256, 0, stream>>>(x, adj_w, pAj);
    k2_gemm<<<256, 256, 0, stream>>>(x, adj_w, adj_b, weight, pAj,
                                     out, dis, aib, pS0, pS1);
    k3_final<<<256, 256, 0, stream>>>(dis, aib, pS0, pS1, bias, out);
}